// Round 1
// baseline (1141.148 us; speedup 1.0000x reference)
//
#include <hip/hip_runtime.h>
#include <math.h>

#define P_TOTAL 147456
#define HW 9216
#define CHW (512*9216)
#define C_DIM 512
#define KP 64

__device__ __forceinline__ unsigned f2key(float f) {
    unsigned u = __float_as_uint(f);
    return (u & 0x80000000u) ? ~u : (u | 0x80000000u);
}

// ---------- K0: transpose protos to [side][c][k] and init pwork copy ----------
__global__ void k_init(const float* __restrict__ fg, const float* __restrict__ bg,
                       float* __restrict__ protoT, float* __restrict__ pwork) {
    int i = blockIdx.x * 256 + threadIdx.x;   // 0..65535
    int side = i >> 15;
    int r = i & 32767;
    int k = r >> 9;
    int c = r & 511;
    float v = (side ? bg : fg)[k * 512 + c];
    protoT[side * 32768 + c * 64 + k] = v;
    pwork[side * 32768 + k * 512 + c] = v;
}

// ---------- K1: per-point max dot vs 64 protos (one side per blockIdx.y) + norm2 ----------
__global__ __launch_bounds__(256) void k_score(const float* __restrict__ F,
                                               const float* __restrict__ protoT,
                                               float* __restrict__ md_fg,
                                               float* __restrict__ md_bg,
                                               float* __restrict__ n2out) {
    __shared__ float lds[2048];
    const int side = blockIdx.y;
    const int p = blockIdx.x * 256 + threadIdx.x;
    const int n = p / HW;
    const int hw = p - n * HW;
    const float* Fp = F + (size_t)n * CHW + hw;
    const float* PT = protoT + side * (C_DIM * 64);

    float acc[64];
#pragma unroll
    for (int k = 0; k < 64; ++k) acc[k] = 0.f;
    float n2 = 0.f;

    for (int cc = 0; cc < 16; ++cc) {
        __syncthreads();
#pragma unroll
        for (int i = 0; i < 8; ++i)
            lds[threadIdx.x + 256 * i] = PT[cc * 2048 + threadIdx.x + 256 * i];
        __syncthreads();
        for (int c = 0; c < 32; ++c) {
            float f = Fp[(size_t)(cc * 32 + c) * HW];
            if (side == 0) n2 = fmaf(f, f, n2);
#pragma unroll
            for (int k = 0; k < 64; ++k) acc[k] = fmaf(f, lds[c * 64 + k], acc[k]);
        }
    }
    float m = acc[0];
#pragma unroll
    for (int k = 1; k < 64; ++k) m = fmaxf(m, acc[k]);
    if (side == 0) { md_fg[p] = m; n2out[p] = n2; }
    else          { md_bg[p] = m; }
}

// ---------- K1b: combine -> scores (in place) and inv_norm ----------
__global__ void k_combine(const float* __restrict__ M,
                          float* __restrict__ sfg, float* __restrict__ sbg,
                          float* __restrict__ n2inv) {
    int p = blockIdx.x * 256 + threadIdx.x;
    float inv = 1.f / fmaxf(sqrtf(n2inv[p]), 1e-8f);
    float m = fminf(fmaxf(M[p], 0.f), 1.f);
    float sf = (1.f - sfg[p] * inv) * m;
    float sb = (1.f - sbg[p] * inv) * (1.f - m);
    sfg[p] = sf; sbg[p] = sb; n2inv[p] = inv;
}

// ---------- histogram passes for exact radix top-256 ----------
__global__ void k_hist1(const float* __restrict__ sfg, const float* __restrict__ sbg,
                        unsigned* __restrict__ hist) {
    int side = blockIdx.y;
    int p = blockIdx.x * 256 + threadIdx.x;
    float s = side ? sbg[p] : sfg[p];
    atomicAdd(&hist[side * 65536 + (f2key(s) >> 16)], 1u);
}

__global__ void k_hist2(const float* __restrict__ sfg, const float* __restrict__ sbg,
                        const int* __restrict__ ctrl, unsigned* __restrict__ hist2) {
    int side = blockIdx.y;
    int p = blockIdx.x * 256 + threadIdx.x;
    float s = side ? sbg[p] : sfg[p];
    unsigned key = f2key(s);
    if ((int)(key >> 16) == ctrl[side * 8 + 0])
        atomicAdd(&hist2[side * 65536 + (key & 0xffffu)], 1u);
}

// ---------- scan: find threshold bucket (pass 0) / exact key (pass 1) ----------
__global__ __launch_bounds__(1024) void k_scan(const unsigned* __restrict__ hist,
                                               int* __restrict__ ctrl, int pass) {
    __shared__ unsigned sd[1024];
    int side = blockIdx.x;
    const unsigned* h = hist + side * 65536;
    int t = threadIdx.x;
    unsigned partial = 0;
    for (int j = 0; j < 64; ++j) partial += h[65535 - (t * 64 + j)];
    sd[t] = partial;
    __syncthreads();
    for (int off = 1; off < 1024; off <<= 1) {
        unsigned v = (t >= off) ? sd[t - off] : 0u;
        __syncthreads();
        sd[t] += v;
        __syncthreads();
    }
    unsigned incl = sd[t];
    unsigned excl = incl - partial;
    unsigned target = (pass == 0) ? 256u : (unsigned)ctrl[side * 8 + 1];
    if (excl < target && target <= incl) {
        unsigned cum = excl;
        for (int j = 0; j < 64; ++j) {
            int b = 65535 - (t * 64 + j);
            unsigned c = h[b];
            if (cum + c >= target) {
                if (pass == 0) {
                    ctrl[side * 8 + 0] = b;
                    ctrl[side * 8 + 1] = (int)(target - cum);
                } else {
                    unsigned vkey = ((unsigned)ctrl[side * 8 + 0] << 16) | (unsigned)b;
                    ctrl[side * 8 + 2] = (int)vkey;
                    int n_gt = (int)(256u - (unsigned)ctrl[side * 8 + 1] + cum);
                    ctrl[side * 8 + 3] = n_gt;
                    ctrl[side * 8 + 4] = 256 - n_gt;
                }
                break;
            }
            cum += c;
        }
    }
}

// ---------- collect indices ----------
__global__ void k_collect(const float* __restrict__ sfg, const float* __restrict__ sbg,
                          int* __restrict__ ctrl, int* __restrict__ idx, int* __restrict__ ties) {
    int side = blockIdx.y;
    int p = blockIdx.x * 256 + threadIdx.x;
    float s = side ? sbg[p] : sfg[p];
    unsigned key = f2key(s);
    unsigned vkey = (unsigned)ctrl[side * 8 + 2];
    if (key > vkey) {
        int pos = atomicAdd(&ctrl[side * 8 + 5], 1);
        idx[side * 256 + pos] = p;
    } else if (key == vkey) {
        int pos = atomicAdd(&ctrl[side * 8 + 6], 1);
        if (pos < 512) ties[side * 512 + pos] = p;
    }
}

// ---------- tie finalize: smallest indices first (matches jax top_k) ----------
__global__ void k_finalize(int* __restrict__ ctrl, int* __restrict__ idx, int* __restrict__ ties) {
    int side = threadIdx.x;
    if (side >= 2) return;
    int n_gt = ctrl[side * 8 + 3];
    int need = ctrl[side * 8 + 4];
    int cnt = ctrl[side * 8 + 6];
    if (cnt > 512) cnt = 512;
    int* tb = ties + side * 512;
    for (int q = 0; q < need; ++q) {
        int mi = q;
        for (int j = q + 1; j < cnt; ++j) if (tb[j] < tb[mi]) mi = j;
        int tmp = tb[q]; tb[q] = tb[mi]; tb[mi] = tmp;
        idx[side * 256 + n_gt + q] = tb[q];
    }
}

// ---------- gather normalized selected features ----------
__global__ void k_gather(const float* __restrict__ F, const float* __restrict__ inv,
                         const int* __restrict__ idx, float* __restrict__ feats) {
    int b = blockIdx.x;              // 0..511
    int side = b >> 8, j = b & 255;
    int p = idx[side * 256 + j];
    float iv = inv[p];
    int n = p / HW, hw = p - n * HW;
    const float* Fp = F + (size_t)n * CHW + hw;
    float* o = feats + (size_t)(side * 256 + j) * 512;
    for (int c = threadIdx.x; c < 512; c += 256)
        o[c] = Fp[(size_t)c * HW] * iv;
}

// ---------- refinement: assign (wave per point, lane = cluster) ----------
__global__ __launch_bounds__(256) void k_assign(const float* __restrict__ feats,
                                                const float* __restrict__ pwork,
                                                float* __restrict__ sums,
                                                float* __restrict__ counts) {
    int w = blockIdx.x * 4 + (threadIdx.x >> 6);   // 0..511
    int lane = threadIdx.x & 63;
    int side = w >> 8, j = w & 255;
    const float4* fr = (const float4*)(feats + (size_t)(side * 256 + j) * 512);
    const float4* pw = (const float4*)(pwork + (size_t)side * 32768 + (size_t)lane * 512);
    float dot = 0.f;
#pragma unroll 4
    for (int c = 0; c < 128; ++c) {
        float4 a = fr[c], b = pw[c];
        dot = fmaf(a.x, b.x, dot); dot = fmaf(a.y, b.y, dot);
        dot = fmaf(a.z, b.z, dot); dot = fmaf(a.w, b.w, dot);
    }
    float bv = dot; int bi = lane;
#pragma unroll
    for (int m = 32; m >= 1; m >>= 1) {
        float ov = __shfl_xor(bv, m);
        int oi = __shfl_xor(bi, m);
        if (ov > bv || (ov == bv && oi < bi)) { bv = ov; bi = oi; }
    }
    if (lane == 0) atomicAdd(&counts[side * 64 + bi], 1.f);
    const float* frf = feats + (size_t)(side * 256 + j) * 512;
    float* srow = sums + (size_t)side * 32768 + (size_t)bi * 512;
#pragma unroll
    for (int i = 0; i < 8; ++i) {
        int c = lane + i * 64;
        atomicAdd(&srow[c], frf[c]);
    }
}

// ---------- refinement: update protos (wave per cluster), zero sums for next iter ----------
__global__ __launch_bounds__(64) void k_update(float* __restrict__ pwork,
                                               float* __restrict__ sums,
                                               float* __restrict__ counts,
                                               float step) {
    int side = blockIdx.x >> 6, k = blockIdx.x & 63;
    int lane = threadIdx.x;
    float cnt = counts[side * 64 + k];
    float* srow = sums + (size_t)side * 32768 + (size_t)k * 512;
    float* prow = pwork + (size_t)side * 32768 + (size_t)k * 512;
    float bl[8]; float n2 = 0.f;
#pragma unroll
    for (int i = 0; i < 8; ++i) {
        int c = lane + i * 64;
        float mean = srow[c] / fmaxf(cnt, 1.f);
        float v = (1.f - step) * prow[c] + step * mean;
        bl[i] = v; n2 = fmaf(v, v, n2);
        srow[c] = 0.f;
    }
#pragma unroll
    for (int m = 32; m >= 1; m >>= 1) n2 += __shfl_xor(n2, m);
    float inv = 1.f / fmaxf(sqrtf(n2), 1e-8f);
    if (cnt > 0.f) {
#pragma unroll
        for (int i = 0; i < 8; ++i) prow[lane + i * 64] = bl[i] * inv;
    }
    if (lane == 0) counts[side * 64 + k] = 0.f;
}

// ---------- loss partials: wave per row ----------
__global__ __launch_bounds__(256) void k_losspart(const float* __restrict__ feats,
                                                  const float* __restrict__ pwork,
                                                  float* __restrict__ lpart) {
    int w = blockIdx.x * 4 + (threadIdx.x >> 6);  // 0..511
    int lane = threadIdx.x & 63;
    int half = w >> 8, j = w & 255;
    const float4* fr = (const float4*)(feats + (size_t)(half * 256 + j) * 512);
    const float4* pf = (const float4*)(pwork + (size_t)lane * 512);
    const float4* pb = (const float4*)(pwork + 32768 + (size_t)lane * 512);
    if (half == 0) {
        float d1 = 0.f, d2 = 0.f;
        for (int c = 0; c < 128; ++c) {
            float4 a = fr[c], x = pf[c], y = pb[c];
            d1 = fmaf(a.x, x.x, d1); d1 = fmaf(a.y, x.y, d1);
            d1 = fmaf(a.z, x.z, d1); d1 = fmaf(a.w, x.w, d1);
            d2 = fmaf(a.x, y.x, d2); d2 = fmaf(a.y, y.y, d2);
            d2 = fmaf(a.z, y.z, d2); d2 = fmaf(a.w, y.w, d2);
        }
        float smax = d1;
        for (int m = 32; m >= 1; m >>= 1) smax = fmaxf(smax, __shfl_xor(smax, m));
        float a = d1 / 0.07f, b = d2 / 0.07f;
        float m1 = a;
        for (int m = 32; m >= 1; m >>= 1) m1 = fmaxf(m1, __shfl_xor(m1, m));
        float mb = b;
        for (int m = 32; m >= 1; m >>= 1) mb = fmaxf(mb, __shfl_xor(mb, m));
        float md = fmaxf(m1, mb);
        float sn = expf(a - m1);
        for (int m = 32; m >= 1; m >>= 1) sn += __shfl_xor(sn, m);
        float sdn = expf(a - md) + expf(b - md);
        for (int m = 32; m >= 1; m >>= 1) sdn += __shfl_xor(sdn, m);
        float num = m1 + logf(sn);
        float den = md + logf(sdn);
        if (lane == 0) { lpart[j] = smax; lpart[512 + j] = num - den; }
    } else {
        float d1 = 0.f;
        for (int c = 0; c < 128; ++c) {
            float4 a = fr[c], x = pf[c];
            d1 = fmaf(a.x, x.x, d1); d1 = fmaf(a.y, x.y, d1);
            d1 = fmaf(a.z, x.z, d1); d1 = fmaf(a.w, x.w, d1);
        }
        float smax = d1;
        for (int m = 32; m >= 1; m >>= 1) smax = fmaxf(smax, __shfl_xor(smax, m));
        if (lane == 0) lpart[256 + j] = smax;
    }
}

// ---------- final scalar loss ----------
__global__ __launch_bounds__(256) void k_final(const float* __restrict__ lpart,
                                               float* __restrict__ out) {
    __shared__ float red[3][4];
    int t = threadIdx.x;
    float sp = lpart[t], sn = lpart[256 + t], nm = lpart[512 + t];
    for (int m = 32; m >= 1; m >>= 1) {
        sp += __shfl_xor(sp, m); sn += __shfl_xor(sn, m); nm += __shfl_xor(nm, m);
    }
    int wv = t >> 6;
    if ((t & 63) == 0) { red[0][wv] = sp; red[1][wv] = sn; red[2][wv] = nm; }
    __syncthreads();
    if (t == 0) {
        float SP = 0, SN = 0, NM = 0;
        for (int i = 0; i < 4; ++i) { SP += red[0][i]; SN += red[1][i]; NM += red[2][i]; }
        SP /= 256.f; SN /= 256.f; NM /= 256.f;
        out[0] = fmaxf(0.f, 0.2f + SN - SP) + 0.25f * (-NM);
    }
}

// ---------- blended refined protos ----------
__global__ __launch_bounds__(64) void k_refined(const float* __restrict__ fg,
                                                const float* __restrict__ bg,
                                                const float* __restrict__ pwork,
                                                float* __restrict__ out) {
    int side = blockIdx.x >> 6, k = blockIdx.x & 63;
    int lane = threadIdx.x;
    const float* proto = (side ? bg : fg) + (size_t)k * 512;
    const float* prow = pwork + (size_t)side * 32768 + (size_t)k * 512;
    float bl[8]; float n2 = 0.f;
#pragma unroll
    for (int i = 0; i < 8; ++i) {
        int c = lane + i * 64;
        float v = 0.7f * proto[c] + 0.3f * prow[c];
        bl[i] = v; n2 = fmaf(v, v, n2);
    }
#pragma unroll
    for (int m = 32; m >= 1; m >>= 1) n2 += __shfl_xor(n2, m);
    float inv = 1.f / fmaxf(sqrtf(n2), 1e-8f);
    float* o = out + 1 + (size_t)side * 32768 + (size_t)k * 512;
#pragma unroll
    for (int i = 0; i < 8; ++i) o[lane + i * 64] = bl[i] * inv;
}

extern "C" void kernel_launch(void* const* d_in, const int* in_sizes, int n_in,
                              void* d_out, int out_size, void* d_ws, size_t ws_size,
                              hipStream_t stream) {
    const float* fg = (const float*)d_in[0];
    const float* bg = (const float*)d_in[1];
    const float* F  = (const float*)d_in[2];
    const float* M  = (const float*)d_in[3];
    float* out = (float*)d_out;
    char* ws = (char*)d_ws;

    size_t o = 0;
    auto alloc = [&](size_t bytes) { size_t r = o; o += (bytes + 1023) & ~(size_t)1023; return r; };
    // zero region first (one memset covers all of it)
    size_t off_hist1 = alloc(2 * 65536 * 4);
    size_t off_hist2 = alloc(2 * 65536 * 4);
    size_t off_ctrl  = alloc(64);
    size_t off_cnts  = alloc(2 * 64 * 4);
    size_t off_sums  = alloc(2 * 64 * 512 * 4);
    size_t zbytes = o;
    size_t off_sfg   = alloc(P_TOTAL * 4);
    size_t off_sbg   = alloc(P_TOTAL * 4);
    size_t off_n2    = alloc(P_TOTAL * 4);
    size_t off_pT    = alloc(2 * 512 * 64 * 4);
    size_t off_idx   = alloc(2 * 256 * 4);
    size_t off_ties  = alloc(2 * 512 * 4);
    size_t off_feats = alloc(2 * 256 * 512 * 4);
    size_t off_pwork = alloc(2 * 64 * 512 * 4);
    size_t off_lpart = alloc(768 * 4);

    unsigned* hist1 = (unsigned*)(ws + off_hist1);
    unsigned* hist2 = (unsigned*)(ws + off_hist2);
    int* ctrl   = (int*)(ws + off_ctrl);
    float* cnts = (float*)(ws + off_cnts);
    float* sums = (float*)(ws + off_sums);
    float* sfg  = (float*)(ws + off_sfg);
    float* sbg  = (float*)(ws + off_sbg);
    float* n2   = (float*)(ws + off_n2);
    float* pT   = (float*)(ws + off_pT);
    int* idx    = (int*)(ws + off_idx);
    int* ties   = (int*)(ws + off_ties);
    float* feats = (float*)(ws + off_feats);
    float* pwork = (float*)(ws + off_pwork);
    float* lpart = (float*)(ws + off_lpart);

    hipMemsetAsync(ws, 0, zbytes, stream);
    k_init<<<256, 256, 0, stream>>>(fg, bg, pT, pwork);
    k_score<<<dim3(576, 2), 256, 0, stream>>>(F, pT, sfg, sbg, n2);
    k_combine<<<576, 256, 0, stream>>>(M, sfg, sbg, n2);
    k_hist1<<<dim3(576, 2), 256, 0, stream>>>(sfg, sbg, hist1);
    k_scan<<<2, 1024, 0, stream>>>(hist1, ctrl, 0);
    k_hist2<<<dim3(576, 2), 256, 0, stream>>>(sfg, sbg, ctrl, hist2);
    k_scan<<<2, 1024, 0, stream>>>(hist2, ctrl, 1);
    k_collect<<<dim3(576, 2), 256, 0, stream>>>(sfg, sbg, ctrl, idx, ties);
    k_finalize<<<1, 64, 0, stream>>>(ctrl, idx, ties);
    k_gather<<<512, 256, 0, stream>>>(F, n2, idx, feats);
    for (int it = 0; it < 10; ++it) {
        k_assign<<<128, 256, 0, stream>>>(feats, pwork, sums, cnts);
        k_update<<<128, 64, 0, stream>>>(pwork, sums, cnts, (float)(0.1 / (1.0 + 0.5 * it)));
    }
    k_losspart<<<128, 256, 0, stream>>>(feats, pwork, lpart);
    k_final<<<1, 256, 0, stream>>>(lpart, out);
    k_refined<<<128, 64, 0, stream>>>(fg, bg, pwork, out);
}